// Round 9
// baseline (462.724 us; speedup 1.0000x reference)
//
#include <hip/hip_runtime.h>
#include <math.h>

#define EMBED 128
#define BMAX 8192    // blockmax array (fused grid = ceil(N/16) = 6250 <= BMAX)
#define LDSPAD 136   // 128 + 8 bf16 pad -> 272 B row stride
#define DBINS 64     // degree bins for counting sort (deg clamped to 63)

#define TWO_LOG2E 2.8853900817779268f
#define DEFER_THR 32.0f

// (tail, rel) packed: tail in bits [0,20), rel in bits [20,32). Requires
// N < 2^20 (here N=100000) and R < 2^12 (here 64).
#define TMASK 0xFFFFF

typedef __attribute__((ext_vector_type(8))) short short8;
typedef __attribute__((ext_vector_type(4))) float floatx4;

__device__ __forceinline__ float ex2(float x) { return __builtin_amdgcn_exp2f(x); }

__device__ __forceinline__ float fast_tanh2(float x) {     // 1 mul + 1 exp + 1 rcp
    float e = ex2(TWO_LOG2E * x);                           // x<<0 -> 0 -> -1; x>>0 -> inf -> 1
    return 1.0f - 2.0f * __builtin_amdgcn_rcpf(1.0f + e);
}

__device__ __forceinline__ unsigned short f2b(float f) {   // fp32 -> bf16 RNE
    union { float f; unsigned int u; } v; v.f = f;
    unsigned int r = v.u + 0x7FFFu + ((v.u >> 16) & 1u);
    return (unsigned short)(r >> 16);
}

__device__ __forceinline__ float b2f(short u) {
    union { float f; unsigned int i; } v;
    v.i = ((unsigned int)(unsigned short)u) << 16;
    return v.f;
}

// sum over the 16-lane DPP row via sum-of-rotations (exact allreduce)
template <int CTRL>
__device__ __forceinline__ float dpp_add_f(float x) {
    int y = __builtin_amdgcn_update_dpp(0, __float_as_int(x), CTRL, 0xF, 0xF, false);
    return x + __int_as_float(y);
}
__device__ __forceinline__ float dpp_sum16(float s) {
    s = dpp_add_f<0x121>(s);   // row_ror:1
    s = dpp_add_f<0x122>(s);   // row_ror:2
    s = dpp_add_f<0x124>(s);   // row_ror:4
    s = dpp_add_f<0x128>(s);   // row_ror:8
    return s;
}

// ---------------- K0: cast ent/rel/W to bf16 + head histogram (+ zero ghist) ----------------
__global__ __launch_bounds__(256) void k_cast_hist(
    const float* __restrict__ ent, const float* __restrict__ rel, const float* __restrict__ W,
    short* __restrict__ entb, short* __restrict__ relb, short* __restrict__ wb,
    const int* __restrict__ heads, int* __restrict__ cnt, int* __restrict__ ghist,
    int ngE, int ngR, int ngW, int E)
{
    if (blockIdx.x == 0 && threadIdx.x < DBINS) ghist[threadIdx.x] = 0;  // no reader until k_scan1
    int stride = gridDim.x * 256;
    int total = ngE + ngR + ngW;
    for (int g = blockIdx.x * 256 + threadIdx.x; g < total; g += stride) {
        const float4* src; short* dst;
        if (g < ngE)            { src = (const float4*)ent + (size_t)g * 2;              dst = entb + (size_t)g * 8; }
        else if (g < ngE + ngR) { int g2 = g - ngE;       src = (const float4*)rel + (size_t)g2 * 2; dst = relb + (size_t)g2 * 8; }
        else                    { int g2 = g - ngE - ngR; src = (const float4*)W   + (size_t)g2 * 2; dst = wb   + (size_t)g2 * 8; }
        float4 a = src[0], b = src[1];
        short8 o;
        o[0] = (short)f2b(a.x); o[1] = (short)f2b(a.y); o[2] = (short)f2b(a.z); o[3] = (short)f2b(a.w);
        o[4] = (short)f2b(b.x); o[5] = (short)f2b(b.y); o[6] = (short)f2b(b.z); o[7] = (short)f2b(b.w);
        *(short8*)dst = o;
    }
    for (int e = blockIdx.x * 256 + threadIdx.x; e < E; e += stride)
        atomicAdd(cnt + heads[e], 1);
}

// ---------------- K1a: block scan of cnt + degree histogram ----------------
__global__ __launch_bounds__(1024) void k_scan1(
    const int* __restrict__ cnt, int* __restrict__ offs,
    int* __restrict__ bsum, int* __restrict__ ghist, int N)
{
    __shared__ int wsum[16];
    __shared__ int dh[DBINS];
    const int tid = threadIdx.x;
    if (tid < DBINS) dh[tid] = 0;
    int i = blockIdx.x * 1024 + tid;
    int v = (i < N) ? cnt[i] : 0;
    __syncthreads();
    if (i < N) atomicAdd(&dh[v < DBINS ? v : DBINS - 1], 1);
    int x = v;
    #pragma unroll
    for (int d = 1; d < 64; d <<= 1) {
        int y = __shfl_up(x, d, 64);
        if ((tid & 63) >= d) x += y;
    }
    if ((tid & 63) == 63) wsum[tid >> 6] = x;
    __syncthreads();
    if (tid < 16) {
        int w = wsum[tid];
        #pragma unroll
        for (int d = 1; d < 16; d <<= 1) {
            int y = __shfl_up(w, d, 16);
            if (tid >= d) w += y;
        }
        wsum[tid] = w;
    }
    __syncthreads();
    int add = (tid >= 64) ? wsum[(tid >> 6) - 1] : 0;
    int incl = x + add;
    if (i < N) offs[i] = incl - v;
    if (tid == 1023) bsum[blockIdx.x] = incl;
    if (tid < DBINS && dh[tid] > 0) atomicAdd(ghist + tid, dh[tid]);
}

// ---------------- K1b: finalize offs/cursor + counting-sort scatter (scan2 folded in) ----------------
__global__ __launch_bounds__(256) void k_scan23(
    int* __restrict__ offs, const int* __restrict__ bsum,
    int* __restrict__ cursor, const int* __restrict__ cnt,
    const int* __restrict__ ghist, int* __restrict__ bincur,
    int* __restrict__ order, int N, int nb)
{
    __shared__ int sb[256];      // exclusive-scanned bsum
    __shared__ int ws4[4];
    __shared__ int dbs[DBINS];   // exclusive-scanned ghist
    __shared__ int lcnt[DBINS];
    __shared__ int lbase[DBINS];
    const int tid = threadIdx.x;

    int v = (tid < nb) ? bsum[tid] : 0;
    int x = v;
    #pragma unroll
    for (int d = 1; d < 64; d <<= 1) {
        int y = __shfl_up(x, d, 64);
        if ((tid & 63) >= d) x += y;
    }
    if ((tid & 63) == 63) ws4[tid >> 6] = x;
    __syncthreads();
    if (tid < 4) {
        int w = ws4[tid];
        #pragma unroll
        for (int d = 1; d < 4; d <<= 1) {
            int y = __shfl_up(w, d, 4);
            if (tid >= d) w += y;
        }
        ws4[tid] = w;
    }
    __syncthreads();
    int add = (tid >= 64) ? ws4[(tid >> 6) - 1] : 0;
    sb[tid] = x + add - v;            // exclusive prefix of bsum

    if (tid < 64) {                   // ghist exclusive scan (one wave)
        int g = ghist[tid];
        int s = g;
        #pragma unroll
        for (int d = 1; d < 64; d <<= 1) {
            int y = __shfl_up(s, d, 64);
            if (tid >= d) s += y;
        }
        dbs[tid] = s - g;
    }
    if (tid < DBINS) lcnt[tid] = 0;
    __syncthreads();

    int i = blockIdx.x * 256 + tid;
    int deg = 0, lrank = 0;
    if (i < N) {
        int o = offs[i] + sb[i >> 10];
        offs[i] = o;
        cursor[i] = o;
        int c = cnt[i];
        deg = c < DBINS ? c : DBINS - 1;
        lrank = atomicAdd(&lcnt[deg], 1);          // local rank within block
    }
    __syncthreads();
    if (tid < DBINS) {
        int n = lcnt[tid];
        lbase[tid] = (n > 0) ? (dbs[tid] + atomicAdd(bincur + tid, n)) : 0;
    }
    __syncthreads();
    if (i < N) order[lbase[deg] + lrank] = i;
}

// ---------------- K2: CSR slot-fill: packed tail|rel<<20 per slot ----------------
__global__ __launch_bounds__(256) void k_csr(
    const int* __restrict__ heads, const int* __restrict__ rels,
    const int* __restrict__ tails, int* __restrict__ cursor,
    int* __restrict__ trp, int E)
{
    int e = blockIdx.x * 256 + threadIdx.x;
    if (e >= E) return;
    int pos = atomicAdd(cursor + heads[e], 1);
    trp[pos] = tails[e] | (rels[e] << 20);
}

// ---------------- K3: fused score + online-softmax aggregate ----------------
// 16 lanes per head; DESCENDING degree order (LPT). j-body identical to the
// verified r8 kernel. Global max M computed in-kernel by the LAST block
// (threadfence + atomicAdd(done) pattern) -- k_maxred launch eliminated.
__global__ __launch_bounds__(256) void k_fused(
    const short* __restrict__ entb, const short* __restrict__ relb,
    const int* __restrict__ offs, const int* __restrict__ cnt,
    const int* __restrict__ trp, const int* __restrict__ order,
    short* __restrict__ accb, float* __restrict__ mh, float* __restrict__ lh,
    float* __restrict__ blockmax, unsigned int* __restrict__ done,
    float* __restrict__ Mout, int N, int R)
{
    const int tid = threadIdx.x;
    const int lane = tid & 15;
    int head0 = blockIdx.x * 16 + (tid >> 4);
    int head  = (head0 < N) ? order[(N - 1) - head0] : N;   // reverse = descending degree
    float mt = -INFINITY;              // true max (for global M)
    if (head < N) {
        int start = offs[head];
        int c     = cnt[head];
        short8 hh = *((const short8*)(entb + (size_t)head * EMBED) + lane);
        float hf[8];
        #pragma unroll
        for (int i = 0; i < 8; ++i) hf[i] = b2f(hh[i]);
        float m = -INFINITY;           // deferred reference point
        float l = 0.f;
        float acc[8] = {0,0,0,0,0,0,0,0};
        for (int base = 0; base < c; base += 16) {
            int rem = c - base;
            int mm  = rem < 16 ? rem : 16;
            int trv = 0;
            if (lane < mm) trv = trp[start + base + lane];
            int p0 = __shfl(trv, 0, 16);
            short8 vtc = *((const short8*)(entb + (size_t)(p0 & TMASK) * EMBED) + lane);
            short8 vrc = *((const short8*)(relb + (size_t)(p0 >> 20) * EMBED) + lane);
            for (int j = 0; j < mm; ++j) {
                int jn = (j + 1 < mm) ? j + 1 : j;       // clamp: last iter reloads (L1-hot)
                int pn = __shfl(trv, jn, 16);
                short8 vtn = *((const short8*)(entb + (size_t)(pn & TMASK) * EMBED) + lane);
                short8 vrn = *((const short8*)(relb + (size_t)(pn >> 20) * EMBED) + lane);
                float s = 0.f;
                float vtf[8];
                #pragma unroll
                for (int i = 0; i < 8; ++i) {
                    vtf[i] = b2f(vtc[i]);
                    s = fmaf(vtf[i], fast_tanh2(hf[i] + b2f(vrc[i])), s);
                }
                s = dpp_sum16(s);
                mt = fmaxf(mt, s);
                float dlt = s - m;                 // first edge: +inf
                if (dlt > DEFER_THR) {             // rare after j=0 (j=0 synchronized)
                    float alpha = __expf(-dlt);    // exp(m - s); -inf -> 0
                    l *= alpha;
                    #pragma unroll
                    for (int q = 0; q < 8; ++q) acc[q] *= alpha;
                    m = s;
                    dlt = 0.f;
                }
                float p = __expf(dlt);             // p <= e^32: fp32-safe
                l += p;
                #pragma unroll
                for (int q = 0; q < 8; ++q)
                    acc[q] = fmaf(p, vtf[q], acc[q]);
                vtc = vtn;
                vrc = vrn;
            }
        }
        short8 o;
        #pragma unroll
        for (int q = 0; q < 8; ++q) o[q] = (short)f2b(acc[q]);
        *((short8*)(accb + (size_t)head * EMBED) + lane) = o;
        if (lane == 0) { mh[head] = m; lh[head] = l; }
    }
    // block max: wave shfl_xor reduce + 4-slot LDS + one barrier
    __shared__ float wmax[4];
    __shared__ int lastflag;
    float wm = mt;
    #pragma unroll
    for (int off = 1; off < 64; off <<= 1) wm = fmaxf(wm, __shfl_xor(wm, off, 64));
    if ((tid & 63) == 0) wmax[tid >> 6] = wm;
    __syncthreads();
    if (tid == 0) {
        blockmax[blockIdx.x] = fmaxf(fmaxf(wmax[0], wmax[1]), fmaxf(wmax[2], wmax[3]));
        __threadfence();                                   // publish blockmax before count
        unsigned int prev = atomicAdd(done, 1u);
        lastflag = (prev == gridDim.x - 1) ? 1 : 0;        // last arriving block reduces
    }
    __syncthreads();
    if (lastflag) {
        __threadfence();                                   // acquire other blocks' writes
        const volatile float* bm = (const volatile float*)blockmax;
        float m2 = -INFINITY;
        for (int i = tid; i < (int)gridDim.x; i += 256) m2 = fmaxf(m2, bm[i]);
        #pragma unroll
        for (int off = 1; off < 64; off <<= 1) m2 = fmaxf(m2, __shfl_xor(m2, off, 64));
        if ((tid & 63) == 0) wmax[tid >> 6] = m2;
        __syncthreads();
        if (tid == 0)
            Mout[0] = fmaxf(fmaxf(wmax[0], wmax[1]), fmaxf(wmax[2], wmax[3]));
    }
}

// ---------------- K4: fused normalize + x = ent + agg + bf16 MFMA GEMM ----------------
// A-fragments built in REGISTERS (no xs LDS round-trip): lane (n16,quad) of
// wave wv handles rows wv*32+n16(+16), cols kc*32+quad*8..+8 -- quads of the
// same row jointly cover full 64B lines, so loads stay coalesced. Math
// bit-identical to the staged version. LDS = ws only (35 KB -> 4 blocks/CU).
__global__ __launch_bounds__(256) void k_gemm_f(
    const short* __restrict__ entb, const short* __restrict__ accb,
    const float* __restrict__ mh, const float* __restrict__ lh,
    const float* __restrict__ Mptr, const short* __restrict__ wb,
    float* __restrict__ out, int N)
{
    __shared__ short ws[128 * LDSPAD];
    __shared__ float invs[128];
    const int tid = threadIdx.x;
    const int n0  = blockIdx.x * 128;
    const float M = Mptr[0];

    if (tid < 128) {
        int g = n0 + tid;
        invs[tid] = (g < N) ? 1.0f / (lh[g] + 1e-10f * __expf(M - mh[g])) : 0.f;  // inf -> 0
    }
    // stage W (pre-cast bf16): 2048 short8 chunks, 8 per thread
    #pragma unroll
    for (int it = 0; it < 8; ++it) {
        int ch = it * 256 + tid;
        int row = ch >> 4, col8 = ch & 15;
        *(short8*)(ws + row * LDSPAD + col8 * 8) = ((const short8*)wb)[ch];
    }
    __syncthreads();

    const int wv   = tid >> 6;
    const int lane = tid & 63;
    const int n16  = lane & 15;
    const int quad = lane >> 4;

    const int lr0 = wv * 32 + n16;        // local row of a0
    const int lr1 = lr0 + 16;             // local row of a1
    const int g0  = n0 + lr0;
    const int g1  = n0 + lr1;

    floatx4 acc[2][8];
    #pragma unroll
    for (int rt = 0; rt < 2; ++rt)
        #pragma unroll
        for (int jt = 0; jt < 8; ++jt)
            acc[rt][jt] = (floatx4){0.f, 0.f, 0.f, 0.f};

    const float inv0 = invs[lr0];
    const float inv1 = invs[lr1];

    #pragma unroll
    for (int kc = 0; kc < 4; ++kc) {
        int koff = kc * 32 + quad * 8;
        short8 a0 = {0,0,0,0,0,0,0,0};
        short8 a1 = {0,0,0,0,0,0,0,0};
        if (g0 < N) {
            short8 e8 = *(const short8*)(entb + (size_t)g0 * EMBED + koff);
            short8 a8 = *(const short8*)(accb + (size_t)g0 * EMBED + koff);
            #pragma unroll
            for (int q = 0; q < 8; ++q)
                a0[q] = (short)f2b(b2f(e8[q]) + b2f(a8[q]) * inv0);
        }
        if (g1 < N) {
            short8 e8 = *(const short8*)(entb + (size_t)g1 * EMBED + koff);
            short8 a8 = *(const short8*)(accb + (size_t)g1 * EMBED + koff);
            #pragma unroll
            for (int q = 0; q < 8; ++q)
                a1[q] = (short)f2b(b2f(e8[q]) + b2f(a8[q]) * inv1);
        }
        #pragma unroll
        for (int jt = 0; jt < 8; ++jt) {
            short8 b = *(const short8*)(ws + (jt * 16 + n16) * LDSPAD + koff);
            acc[0][jt] = __builtin_amdgcn_mfma_f32_16x16x32_bf16(a0, b, acc[0][jt], 0, 0, 0);
            acc[1][jt] = __builtin_amdgcn_mfma_f32_16x16x32_bf16(a1, b, acc[1][jt], 0, 0, 0);
        }
    }

    #pragma unroll
    for (int rt = 0; rt < 2; ++rt) {
        int rowbase = n0 + wv * 32 + rt * 16 + quad * 4;
        #pragma unroll
        for (int r = 0; r < 4; ++r) {
            int grow = rowbase + r;
            if (grow < N) {
                float* o = out + (size_t)grow * EMBED + n16;
                #pragma unroll
                for (int jt = 0; jt < 8; ++jt) {
                    float v = acc[rt][jt][r];
                    o[jt * 16] = (v > 0.f) ? v : 0.2f * v;
                }
            }
        }
    }
}

extern "C" void kernel_launch(void* const* d_in, const int* in_sizes, int n_in,
                              void* d_out, int out_size, void* d_ws, size_t ws_size,
                              hipStream_t stream)
{
    const float* ent   = (const float*)d_in[0];   // entity_emb  [N,128] fp32
    const float* rel   = (const float*)d_in[1];   // rel_embed   [R,128] fp32
    const float* W     = (const float*)d_in[2];   // W           [128,128] fp32
    const int*   heads = (const int*)d_in[3];
    const int*   rels  = (const int*)d_in[4];
    const int*   tails = (const int*)d_in[5];
    const int E = in_sizes[3];
    const int N = in_sizes[0] / EMBED;
    const int R = in_sizes[1] / EMBED;
    float* out = (float*)d_out;

    // ws layout:
    // accb[N*128]s | mh[N]f | lh[N]f | trp[E]i | cnt[N]i | bincur[64]i | done[4]u |
    // offs[N]i | cursor[N]i | blockmax[BMAX]f | Mval[4]f | bsum[1024]i | ghist[64]i |
    // order[N]i | wb[16384]s | entb[N*128]s | relb[R*128]s
    short* accb     = (short*)d_ws;
    float* mh       = (float*)(accb + (size_t)N * EMBED);
    float* lh       = mh + N;
    int*   trp      = (int*)(lh + N);
    int*   cnt      = trp + E;
    int*   bincur   = cnt + N;                      // zeroed together with cnt
    unsigned int* done = (unsigned int*)(bincur + DBINS);   // zeroed together with cnt
    int*   offs     = (int*)(done + 4);
    int*   cursor   = offs + N;
    float* blockmax = (float*)(cursor + N);
    float* Mval     = blockmax + BMAX;
    int*   bsum     = (int*)(Mval + 4);             // 16 B slot keeps alignment
    int*   ghist    = bsum + 1024;
    int*   order    = ghist + DBINS;
    short* wb       = (short*)(order + N);          // 128*128 bf16 = 32 KB
    short* entb     = wb + 16384;
    short* relb     = entb + (size_t)N * EMBED;

    const int nb  = (N + 1023) >> 10;       // scan blocks (<= 256 assumed: N <= 262144)
    const int ngh = (N + 15) / 16;          // per-head group blocks

    hipMemsetAsync(cnt, 0, (size_t)(N + DBINS + 4) * sizeof(int), stream);

    int ngE = N * EMBED / 8, ngR = R * EMBED / 8, ngW = EMBED * EMBED / 8;
    k_cast_hist<<<2048, 256, 0, stream>>>(ent, rel, W, entb, relb, wb, heads, cnt, ghist, ngE, ngR, ngW, E);
    k_scan1<<<nb, 1024, 0, stream>>>(cnt, offs, bsum, ghist, N);
    k_scan23<<<(N + 255) / 256, 256, 0, stream>>>(offs, bsum, cursor, cnt, ghist, bincur, order, N, nb);
    k_csr<<<(E + 255) / 256, 256, 0, stream>>>(heads, rels, tails, cursor, trp, E);
    k_fused<<<ngh, 256, 0, stream>>>(entb, relb, offs, cnt, trp, order, accb, mh, lh, blockmax, done, Mval, N, R);
    k_gemm_f<<<(N + 127) / 128, 256, 0, stream>>>(entb, accb, mh, lh, Mval, wb, out, N);
}

// Round 10
// 243.437 us; speedup vs baseline: 1.9008x; 1.9008x over previous
//
#include <hip/hip_runtime.h>
#include <math.h>

#define EMBED 128
#define BMAX 8192    // blockmax array (fused grid = ceil(N/16) = 6250 <= BMAX)
#define LDSPAD 136   // 128 + 8 bf16 pad -> 272 B row stride
#define DBINS 64     // degree bins for counting sort (deg clamped to 63)

#define TWO_LOG2E 2.8853900817779268f
#define DEFER_THR 32.0f

// (tail, rel) packed: tail in bits [0,20), rel in bits [20,32). Requires
// N < 2^20 (here N=100000) and R < 2^12 (here 64).
#define TMASK 0xFFFFF

typedef __attribute__((ext_vector_type(8))) short short8;
typedef __attribute__((ext_vector_type(4))) float floatx4;

__device__ __forceinline__ float ex2(float x) { return __builtin_amdgcn_exp2f(x); }

__device__ __forceinline__ float fast_tanh2(float x) {     // 1 mul + 1 exp + 1 rcp
    float e = ex2(TWO_LOG2E * x);                           // x<<0 -> 0 -> -1; x>>0 -> inf -> 1
    return 1.0f - 2.0f * __builtin_amdgcn_rcpf(1.0f + e);
}

__device__ __forceinline__ unsigned short f2b(float f) {   // fp32 -> bf16 RNE
    union { float f; unsigned int u; } v; v.f = f;
    unsigned int r = v.u + 0x7FFFu + ((v.u >> 16) & 1u);
    return (unsigned short)(r >> 16);
}

__device__ __forceinline__ float b2f(short u) {
    union { float f; unsigned int i; } v;
    v.i = ((unsigned int)(unsigned short)u) << 16;
    return v.f;
}

// sum over the 16-lane DPP row via sum-of-rotations (exact allreduce)
template <int CTRL>
__device__ __forceinline__ float dpp_add_f(float x) {
    int y = __builtin_amdgcn_update_dpp(0, __float_as_int(x), CTRL, 0xF, 0xF, false);
    return x + __int_as_float(y);
}
__device__ __forceinline__ float dpp_sum16(float s) {
    s = dpp_add_f<0x121>(s);   // row_ror:1
    s = dpp_add_f<0x122>(s);   // row_ror:2
    s = dpp_add_f<0x124>(s);   // row_ror:4
    s = dpp_add_f<0x128>(s);   // row_ror:8
    return s;
}

// ---------------- K0: cast ent/rel/W to bf16 + head histogram (+ zero ghist) ----------------
__global__ __launch_bounds__(256) void k_cast_hist(
    const float* __restrict__ ent, const float* __restrict__ rel, const float* __restrict__ W,
    short* __restrict__ entb, short* __restrict__ relb, short* __restrict__ wb,
    const int* __restrict__ heads, int* __restrict__ cnt, int* __restrict__ ghist,
    int ngE, int ngR, int ngW, int E)
{
    if (blockIdx.x == 0 && threadIdx.x < DBINS) ghist[threadIdx.x] = 0;  // no reader until k_scan1
    int stride = gridDim.x * 256;
    int total = ngE + ngR + ngW;
    for (int g = blockIdx.x * 256 + threadIdx.x; g < total; g += stride) {
        const float4* src; short* dst;
        if (g < ngE)            { src = (const float4*)ent + (size_t)g * 2;              dst = entb + (size_t)g * 8; }
        else if (g < ngE + ngR) { int g2 = g - ngE;       src = (const float4*)rel + (size_t)g2 * 2; dst = relb + (size_t)g2 * 8; }
        else                    { int g2 = g - ngE - ngR; src = (const float4*)W   + (size_t)g2 * 2; dst = wb   + (size_t)g2 * 8; }
        float4 a = src[0], b = src[1];
        short8 o;
        o[0] = (short)f2b(a.x); o[1] = (short)f2b(a.y); o[2] = (short)f2b(a.z); o[3] = (short)f2b(a.w);
        o[4] = (short)f2b(b.x); o[5] = (short)f2b(b.y); o[6] = (short)f2b(b.z); o[7] = (short)f2b(b.w);
        *(short8*)dst = o;
    }
    for (int e = blockIdx.x * 256 + threadIdx.x; e < E; e += stride)
        atomicAdd(cnt + heads[e], 1);
}

// ---------------- K1a: block scan of cnt + degree histogram ----------------
__global__ __launch_bounds__(1024) void k_scan1(
    const int* __restrict__ cnt, int* __restrict__ offs,
    int* __restrict__ bsum, int* __restrict__ ghist, int N)
{
    __shared__ int wsum[16];
    __shared__ int dh[DBINS];
    const int tid = threadIdx.x;
    if (tid < DBINS) dh[tid] = 0;
    int i = blockIdx.x * 1024 + tid;
    int v = (i < N) ? cnt[i] : 0;
    __syncthreads();
    if (i < N) atomicAdd(&dh[v < DBINS ? v : DBINS - 1], 1);
    int x = v;
    #pragma unroll
    for (int d = 1; d < 64; d <<= 1) {
        int y = __shfl_up(x, d, 64);
        if ((tid & 63) >= d) x += y;
    }
    if ((tid & 63) == 63) wsum[tid >> 6] = x;
    __syncthreads();
    if (tid < 16) {
        int w = wsum[tid];
        #pragma unroll
        for (int d = 1; d < 16; d <<= 1) {
            int y = __shfl_up(w, d, 16);
            if (tid >= d) w += y;
        }
        wsum[tid] = w;
    }
    __syncthreads();
    int add = (tid >= 64) ? wsum[(tid >> 6) - 1] : 0;
    int incl = x + add;
    if (i < N) offs[i] = incl - v;
    if (tid == 1023) bsum[blockIdx.x] = incl;
    if (tid < DBINS && dh[tid] > 0) atomicAdd(ghist + tid, dh[tid]);
}

// ---------------- K1b: finalize offs/cursor + counting-sort scatter (scan2 folded in) ----------------
__global__ __launch_bounds__(256) void k_scan23(
    int* __restrict__ offs, const int* __restrict__ bsum,
    int* __restrict__ cursor, const int* __restrict__ cnt,
    const int* __restrict__ ghist, int* __restrict__ bincur,
    int* __restrict__ order, int N, int nb)
{
    __shared__ int sb[256];      // exclusive-scanned bsum
    __shared__ int ws4[4];
    __shared__ int dbs[DBINS];   // exclusive-scanned ghist
    __shared__ int lcnt[DBINS];
    __shared__ int lbase[DBINS];
    const int tid = threadIdx.x;

    int v = (tid < nb) ? bsum[tid] : 0;
    int x = v;
    #pragma unroll
    for (int d = 1; d < 64; d <<= 1) {
        int y = __shfl_up(x, d, 64);
        if ((tid & 63) >= d) x += y;
    }
    if ((tid & 63) == 63) ws4[tid >> 6] = x;
    __syncthreads();
    if (tid < 4) {
        int w = ws4[tid];
        #pragma unroll
        for (int d = 1; d < 4; d <<= 1) {
            int y = __shfl_up(w, d, 4);
            if (tid >= d) w += y;
        }
        ws4[tid] = w;
    }
    __syncthreads();
    int add = (tid >= 64) ? ws4[(tid >> 6) - 1] : 0;
    sb[tid] = x + add - v;            // exclusive prefix of bsum

    if (tid < 64) {                   // ghist exclusive scan (one wave)
        int g = ghist[tid];
        int s = g;
        #pragma unroll
        for (int d = 1; d < 64; d <<= 1) {
            int y = __shfl_up(s, d, 64);
            if (tid >= d) s += y;
        }
        dbs[tid] = s - g;
    }
    if (tid < DBINS) lcnt[tid] = 0;
    __syncthreads();

    int i = blockIdx.x * 256 + tid;
    int deg = 0, lrank = 0;
    if (i < N) {
        int o = offs[i] + sb[i >> 10];
        offs[i] = o;
        cursor[i] = o;
        int c = cnt[i];
        deg = c < DBINS ? c : DBINS - 1;
        lrank = atomicAdd(&lcnt[deg], 1);          // local rank within block
    }
    __syncthreads();
    if (tid < DBINS) {
        int n = lcnt[tid];
        lbase[tid] = (n > 0) ? (dbs[tid] + atomicAdd(bincur + tid, n)) : 0;
    }
    __syncthreads();
    if (i < N) order[lbase[deg] + lrank] = i;
}

// ---------------- K2: CSR slot-fill: packed tail|rel<<20 per slot ----------------
__global__ __launch_bounds__(256) void k_csr(
    const int* __restrict__ heads, const int* __restrict__ rels,
    const int* __restrict__ tails, int* __restrict__ cursor,
    int* __restrict__ trp, int E)
{
    int e = blockIdx.x * 256 + threadIdx.x;
    if (e >= E) return;
    int pos = atomicAdd(cursor + heads[e], 1);
    trp[pos] = tails[e] | (rels[e] << 20);
}

// ---------------- K3: fused score + online-softmax aggregate ----------------
// 16 lanes per head; DESCENDING degree order (LPT). Byte-identical to the
// verified r8 kernel (no fences, no same-address atomics -- r9's in-kernel
// last-block reduce stalled the per-CU VMEM pipe 6x; k_maxred is cheaper).
__global__ __launch_bounds__(256) void k_fused(
    const short* __restrict__ entb, const short* __restrict__ relb,
    const int* __restrict__ offs, const int* __restrict__ cnt,
    const int* __restrict__ trp, const int* __restrict__ order,
    short* __restrict__ accb, float* __restrict__ mh, float* __restrict__ lh,
    float* __restrict__ blockmax, int N, int R)
{
    const int tid = threadIdx.x;
    const int lane = tid & 15;
    int head0 = blockIdx.x * 16 + (tid >> 4);
    int head  = (head0 < N) ? order[(N - 1) - head0] : N;   // reverse = descending degree
    float mt = -INFINITY;              // true max (for global M)
    if (head < N) {
        int start = offs[head];
        int c     = cnt[head];
        short8 hh = *((const short8*)(entb + (size_t)head * EMBED) + lane);
        float hf[8];
        #pragma unroll
        for (int i = 0; i < 8; ++i) hf[i] = b2f(hh[i]);
        float m = -INFINITY;           // deferred reference point
        float l = 0.f;
        float acc[8] = {0,0,0,0,0,0,0,0};
        for (int base = 0; base < c; base += 16) {
            int rem = c - base;
            int mm  = rem < 16 ? rem : 16;
            int trv = 0;
            if (lane < mm) trv = trp[start + base + lane];
            int p0 = __shfl(trv, 0, 16);
            short8 vtc = *((const short8*)(entb + (size_t)(p0 & TMASK) * EMBED) + lane);
            short8 vrc = *((const short8*)(relb + (size_t)(p0 >> 20) * EMBED) + lane);
            for (int j = 0; j < mm; ++j) {
                int jn = (j + 1 < mm) ? j + 1 : j;       // clamp: last iter reloads (L1-hot)
                int pn = __shfl(trv, jn, 16);
                short8 vtn = *((const short8*)(entb + (size_t)(pn & TMASK) * EMBED) + lane);
                short8 vrn = *((const short8*)(relb + (size_t)(pn >> 20) * EMBED) + lane);
                float s = 0.f;
                float vtf[8];
                #pragma unroll
                for (int i = 0; i < 8; ++i) {
                    vtf[i] = b2f(vtc[i]);
                    s = fmaf(vtf[i], fast_tanh2(hf[i] + b2f(vrc[i])), s);
                }
                s = dpp_sum16(s);
                mt = fmaxf(mt, s);
                float dlt = s - m;                 // first edge: +inf
                if (dlt > DEFER_THR) {             // rare after j=0 (j=0 synchronized)
                    float alpha = __expf(-dlt);    // exp(m - s); -inf -> 0
                    l *= alpha;
                    #pragma unroll
                    for (int q = 0; q < 8; ++q) acc[q] *= alpha;
                    m = s;
                    dlt = 0.f;
                }
                float p = __expf(dlt);             // p <= e^32: fp32-safe
                l += p;
                #pragma unroll
                for (int q = 0; q < 8; ++q)
                    acc[q] = fmaf(p, vtf[q], acc[q]);
                vtc = vtn;
                vrc = vrn;
            }
        }
        short8 o;
        #pragma unroll
        for (int q = 0; q < 8; ++q) o[q] = (short)f2b(acc[q]);
        *((short8*)(accb + (size_t)head * EMBED) + lane) = o;
        if (lane == 0) { mh[head] = m; lh[head] = l; }
    }
    // block max: wave shfl_xor reduce + 4-slot LDS + one barrier
    __shared__ float wmax[4];
    float wm = mt;
    #pragma unroll
    for (int off = 1; off < 64; off <<= 1) wm = fmaxf(wm, __shfl_xor(wm, off, 64));
    if ((tid & 63) == 0) wmax[tid >> 6] = wm;
    __syncthreads();
    if (tid == 0)
        blockmax[blockIdx.x] = fmaxf(fmaxf(wmax[0], wmax[1]), fmaxf(wmax[2], wmax[3]));
}

// ---------------- K3b: reduce blockmax -> M ----------------
__global__ __launch_bounds__(256) void k_maxred(
    const float* __restrict__ blockmax, float* __restrict__ Mout, int n)
{
    __shared__ float smax[256];
    float m = -INFINITY;
    for (int i = threadIdx.x; i < n; i += 256) m = fmaxf(m, blockmax[i]);
    smax[threadIdx.x] = m;
    __syncthreads();
    for (int off = 128; off > 0; off >>= 1) {
        if ((int)threadIdx.x < off)
            smax[threadIdx.x] = fmaxf(smax[threadIdx.x], smax[threadIdx.x + off]);
        __syncthreads();
    }
    if (threadIdx.x == 0) Mout[0] = smax[0];
}

// ---------------- K4: fused normalize + x = ent + agg + bf16 MFMA GEMM ----------------
// A-fragments built in REGISTERS (no xs LDS round-trip): lane (n16,quad) of
// wave wv handles rows wv*32+n16(+16), cols kc*32+quad*8..+8 -- quads of the
// same row jointly cover full 64B lines, so loads stay coalesced. Math
// bit-identical to the staged version. LDS = ws only (35 KB -> 4 blocks/CU).
__global__ __launch_bounds__(256) void k_gemm_f(
    const short* __restrict__ entb, const short* __restrict__ accb,
    const float* __restrict__ mh, const float* __restrict__ lh,
    const float* __restrict__ Mptr, const short* __restrict__ wb,
    float* __restrict__ out, int N)
{
    __shared__ short ws[128 * LDSPAD];
    __shared__ float invs[128];
    const int tid = threadIdx.x;
    const int n0  = blockIdx.x * 128;
    const float M = Mptr[0];

    if (tid < 128) {
        int g = n0 + tid;
        invs[tid] = (g < N) ? 1.0f / (lh[g] + 1e-10f * __expf(M - mh[g])) : 0.f;  // inf -> 0
    }
    // stage W (pre-cast bf16): 2048 short8 chunks, 8 per thread
    #pragma unroll
    for (int it = 0; it < 8; ++it) {
        int ch = it * 256 + tid;
        int row = ch >> 4, col8 = ch & 15;
        *(short8*)(ws + row * LDSPAD + col8 * 8) = ((const short8*)wb)[ch];
    }
    __syncthreads();

    const int wv   = tid >> 6;
    const int lane = tid & 63;
    const int n16  = lane & 15;
    const int quad = lane >> 4;

    const int lr0 = wv * 32 + n16;        // local row of a0
    const int lr1 = lr0 + 16;             // local row of a1
    const int g0  = n0 + lr0;
    const int g1  = n0 + lr1;

    floatx4 acc[2][8];
    #pragma unroll
    for (int rt = 0; rt < 2; ++rt)
        #pragma unroll
        for (int jt = 0; jt < 8; ++jt)
            acc[rt][jt] = (floatx4){0.f, 0.f, 0.f, 0.f};

    const float inv0 = invs[lr0];
    const float inv1 = invs[lr1];

    #pragma unroll
    for (int kc = 0; kc < 4; ++kc) {
        int koff = kc * 32 + quad * 8;
        short8 a0 = {0,0,0,0,0,0,0,0};
        short8 a1 = {0,0,0,0,0,0,0,0};
        if (g0 < N) {
            short8 e8 = *(const short8*)(entb + (size_t)g0 * EMBED + koff);
            short8 a8 = *(const short8*)(accb + (size_t)g0 * EMBED + koff);
            #pragma unroll
            for (int q = 0; q < 8; ++q)
                a0[q] = (short)f2b(b2f(e8[q]) + b2f(a8[q]) * inv0);
        }
        if (g1 < N) {
            short8 e8 = *(const short8*)(entb + (size_t)g1 * EMBED + koff);
            short8 a8 = *(const short8*)(accb + (size_t)g1 * EMBED + koff);
            #pragma unroll
            for (int q = 0; q < 8; ++q)
                a1[q] = (short)f2b(b2f(e8[q]) + b2f(a8[q]) * inv1);
        }
        #pragma unroll
        for (int jt = 0; jt < 8; ++jt) {
            short8 b = *(const short8*)(ws + (jt * 16 + n16) * LDSPAD + koff);
            acc[0][jt] = __builtin_amdgcn_mfma_f32_16x16x32_bf16(a0, b, acc[0][jt], 0, 0, 0);
            acc[1][jt] = __builtin_amdgcn_mfma_f32_16x16x32_bf16(a1, b, acc[1][jt], 0, 0, 0);
        }
    }

    #pragma unroll
    for (int rt = 0; rt < 2; ++rt) {
        int rowbase = n0 + wv * 32 + rt * 16 + quad * 4;
        #pragma unroll
        for (int r = 0; r < 4; ++r) {
            int grow = rowbase + r;
            if (grow < N) {
                float* o = out + (size_t)grow * EMBED + n16;
                #pragma unroll
                for (int jt = 0; jt < 8; ++jt) {
                    float v = acc[rt][jt][r];
                    o[jt * 16] = (v > 0.f) ? v : 0.2f * v;
                }
            }
        }
    }
}

extern "C" void kernel_launch(void* const* d_in, const int* in_sizes, int n_in,
                              void* d_out, int out_size, void* d_ws, size_t ws_size,
                              hipStream_t stream)
{
    const float* ent   = (const float*)d_in[0];   // entity_emb  [N,128] fp32
    const float* rel   = (const float*)d_in[1];   // rel_embed   [R,128] fp32
    const float* W     = (const float*)d_in[2];   // W           [128,128] fp32
    const int*   heads = (const int*)d_in[3];
    const int*   rels  = (const int*)d_in[4];
    const int*   tails = (const int*)d_in[5];
    const int E = in_sizes[3];
    const int N = in_sizes[0] / EMBED;
    const int R = in_sizes[1] / EMBED;
    float* out = (float*)d_out;

    // ws layout:
    // accb[N*128]s | mh[N]f | lh[N]f | trp[E]i | cnt[N]i | bincur[64]i | offs[N]i |
    // cursor[N]i | blockmax[BMAX]f | Mval[4]f | bsum[1024]i | ghist[64]i | order[N]i |
    // wb[16384]s | entb[N*128]s | relb[R*128]s
    short* accb     = (short*)d_ws;
    float* mh       = (float*)(accb + (size_t)N * EMBED);
    float* lh       = mh + N;
    int*   trp      = (int*)(lh + N);
    int*   cnt      = trp + E;
    int*   bincur   = cnt + N;                      // zeroed together with cnt
    int*   offs     = bincur + DBINS;
    int*   cursor   = offs + N;
    float* blockmax = (float*)(cursor + N);
    float* Mval     = blockmax + BMAX;
    int*   bsum     = (int*)(Mval + 4);             // 16 B slot keeps alignment
    int*   ghist    = bsum + 1024;
    int*   order    = ghist + DBINS;
    short* wb       = (short*)(order + N);          // 128*128 bf16 = 32 KB
    short* entb     = wb + 16384;
    short* relb     = entb + (size_t)N * EMBED;

    const int nb  = (N + 1023) >> 10;       // scan blocks (<= 256 assumed: N <= 262144)
    const int ngh = (N + 15) / 16;          // per-head group blocks

    hipMemsetAsync(cnt, 0, (size_t)(N + DBINS) * sizeof(int), stream);

    int ngE = N * EMBED / 8, ngR = R * EMBED / 8, ngW = EMBED * EMBED / 8;
    k_cast_hist<<<2048, 256, 0, stream>>>(ent, rel, W, entb, relb, wb, heads, cnt, ghist, ngE, ngR, ngW, E);
    k_scan1<<<nb, 1024, 0, stream>>>(cnt, offs, bsum, ghist, N);
    k_scan23<<<(N + 255) / 256, 256, 0, stream>>>(offs, bsum, cursor, cnt, ghist, bincur, order, N, nb);
    k_csr<<<(E + 255) / 256, 256, 0, stream>>>(heads, rels, tails, cursor, trp, E);
    k_fused<<<ngh, 256, 0, stream>>>(entb, relb, offs, cnt, trp, order, accb, mh, lh, blockmax, N, R);
    k_maxred<<<1, 256, 0, stream>>>(blockmax, Mval, ngh);
    k_gemm_f<<<(N + 127) / 128, 256, 0, stream>>>(entb, accb, mh, lh, Mval, wb, out, N);
}

// Round 11
// 233.462 us; speedup vs baseline: 1.9820x; 1.0427x over previous
//
#include <hip/hip_runtime.h>
#include <math.h>

#define EMBED 128
#define BMAX 8192    // blockmax array (fused grid = ceil(N/16) = 6250 <= BMAX)
#define LDSPAD 136   // 128 + 8 bf16 pad -> 272 B row stride
#define DBINS 64     // degree bins for counting sort (deg clamped to 63)

#define TWO_LOG2E 2.8853900817779268f
#define DEFER_THR 32.0f

// (tail, rel) packed: tail in bits [0,20), rel in bits [20,32). Requires
// N < 2^20 (here N=100000) and R < 2^12 (here 64).
#define TMASK 0xFFFFF

typedef __attribute__((ext_vector_type(8))) short short8;
typedef __attribute__((ext_vector_type(4))) float floatx4;

__device__ __forceinline__ float ex2(float x) { return __builtin_amdgcn_exp2f(x); }

__device__ __forceinline__ unsigned short f2b(float f) {   // fp32 -> bf16 RNE
    union { float f; unsigned int u; } v; v.f = f;
    unsigned int r = v.u + 0x7FFFu + ((v.u >> 16) & 1u);
    return (unsigned short)(r >> 16);
}

__device__ __forceinline__ float b2f(short u) {
    union { float f; unsigned int i; } v;
    v.i = ((unsigned int)(unsigned short)u) << 16;
    return v.f;
}

// sum over the 16-lane DPP row via sum-of-rotations (exact allreduce)
template <int CTRL>
__device__ __forceinline__ float dpp_add_f(float x) {
    int y = __builtin_amdgcn_update_dpp(0, __float_as_int(x), CTRL, 0xF, 0xF, false);
    return x + __int_as_float(y);
}
__device__ __forceinline__ float dpp_sum16(float s) {
    s = dpp_add_f<0x121>(s);   // row_ror:1
    s = dpp_add_f<0x122>(s);   // row_ror:2
    s = dpp_add_f<0x124>(s);   // row_ror:4
    s = dpp_add_f<0x128>(s);   // row_ror:8
    return s;
}

// ---------------- K0: cast ent/W to bf16, build relE = exp2(C*rel) f32 table,
//                     head histogram (+ zero ghist) ----------------
__global__ __launch_bounds__(256) void k_cast_hist(
    const float* __restrict__ ent, const float* __restrict__ rel, const float* __restrict__ W,
    short* __restrict__ entb, short* __restrict__ wb, float* __restrict__ relE,
    const int* __restrict__ heads, int* __restrict__ cnt, int* __restrict__ ghist,
    int ngE, int ngW, int ngX, int E)
{
    if (blockIdx.x == 0 && threadIdx.x < DBINS) ghist[threadIdx.x] = 0;  // no reader until k_scan1
    int stride = gridDim.x * 256;
    int total = ngE + ngW + ngX;
    for (int g = blockIdx.x * 256 + threadIdx.x; g < total; g += stride) {
        if (g < ngE + ngW) {
            const float4* src; short* dst;
            if (g < ngE) { src = (const float4*)ent + (size_t)g * 2;            dst = entb + (size_t)g * 8; }
            else         { int g2 = g - ngE; src = (const float4*)W + (size_t)g2 * 2; dst = wb + (size_t)g2 * 8; }
            float4 a = src[0], b = src[1];
            short8 o;
            o[0] = (short)f2b(a.x); o[1] = (short)f2b(a.y); o[2] = (short)f2b(a.z); o[3] = (short)f2b(a.w);
            o[4] = (short)f2b(b.x); o[5] = (short)f2b(b.y); o[6] = (short)f2b(b.z); o[7] = (short)f2b(b.w);
            *(short8*)dst = o;
        } else {
            int g2 = g - ngE - ngW;
            const float4* src = (const float4*)rel + (size_t)g2 * 2;
            float4 a = src[0], b = src[1];
            float4 ea, eb;
            ea.x = ex2(TWO_LOG2E * a.x); ea.y = ex2(TWO_LOG2E * a.y);
            ea.z = ex2(TWO_LOG2E * a.z); ea.w = ex2(TWO_LOG2E * a.w);
            eb.x = ex2(TWO_LOG2E * b.x); eb.y = ex2(TWO_LOG2E * b.y);
            eb.z = ex2(TWO_LOG2E * b.z); eb.w = ex2(TWO_LOG2E * b.w);
            float4* dst = (float4*)(relE + (size_t)g2 * 8);
            dst[0] = ea; dst[1] = eb;
        }
    }
    for (int e = blockIdx.x * 256 + threadIdx.x; e < E; e += stride)
        atomicAdd(cnt + heads[e], 1);
}

// ---------------- K1a: block scan of cnt + degree histogram ----------------
__global__ __launch_bounds__(1024) void k_scan1(
    const int* __restrict__ cnt, int* __restrict__ offs,
    int* __restrict__ bsum, int* __restrict__ ghist, int N)
{
    __shared__ int wsum[16];
    __shared__ int dh[DBINS];
    const int tid = threadIdx.x;
    if (tid < DBINS) dh[tid] = 0;
    int i = blockIdx.x * 1024 + tid;
    int v = (i < N) ? cnt[i] : 0;
    __syncthreads();
    if (i < N) atomicAdd(&dh[v < DBINS ? v : DBINS - 1], 1);
    int x = v;
    #pragma unroll
    for (int d = 1; d < 64; d <<= 1) {
        int y = __shfl_up(x, d, 64);
        if ((tid & 63) >= d) x += y;
    }
    if ((tid & 63) == 63) wsum[tid >> 6] = x;
    __syncthreads();
    if (tid < 16) {
        int w = wsum[tid];
        #pragma unroll
        for (int d = 1; d < 16; d <<= 1) {
            int y = __shfl_up(w, d, 16);
            if (tid >= d) w += y;
        }
        wsum[tid] = w;
    }
    __syncthreads();
    int add = (tid >= 64) ? wsum[(tid >> 6) - 1] : 0;
    int incl = x + add;
    if (i < N) offs[i] = incl - v;
    if (tid == 1023) bsum[blockIdx.x] = incl;
    if (tid < DBINS && dh[tid] > 0) atomicAdd(ghist + tid, dh[tid]);
}

// ---------------- K1b: finalize offs/cursor + counting-sort scatter (scan2 folded in) ----------------
__global__ __launch_bounds__(256) void k_scan23(
    int* __restrict__ offs, const int* __restrict__ bsum,
    int* __restrict__ cursor, const int* __restrict__ cnt,
    const int* __restrict__ ghist, int* __restrict__ bincur,
    int* __restrict__ order, int N, int nb)
{
    __shared__ int sb[256];      // exclusive-scanned bsum
    __shared__ int ws4[4];
    __shared__ int dbs[DBINS];   // exclusive-scanned ghist
    __shared__ int lcnt[DBINS];
    __shared__ int lbase[DBINS];
    const int tid = threadIdx.x;

    int v = (tid < nb) ? bsum[tid] : 0;
    int x = v;
    #pragma unroll
    for (int d = 1; d < 64; d <<= 1) {
        int y = __shfl_up(x, d, 64);
        if ((tid & 63) >= d) x += y;
    }
    if ((tid & 63) == 63) ws4[tid >> 6] = x;
    __syncthreads();
    if (tid < 4) {
        int w = ws4[tid];
        #pragma unroll
        for (int d = 1; d < 4; d <<= 1) {
            int y = __shfl_up(w, d, 4);
            if (tid >= d) w += y;
        }
        ws4[tid] = w;
    }
    __syncthreads();
    int add = (tid >= 64) ? ws4[(tid >> 6) - 1] : 0;
    sb[tid] = x + add - v;            // exclusive prefix of bsum

    if (tid < 64) {                   // ghist exclusive scan (one wave)
        int g = ghist[tid];
        int s = g;
        #pragma unroll
        for (int d = 1; d < 64; d <<= 1) {
            int y = __shfl_up(s, d, 64);
            if (tid >= d) s += y;
        }
        dbs[tid] = s - g;
    }
    if (tid < DBINS) lcnt[tid] = 0;
    __syncthreads();

    int i = blockIdx.x * 256 + tid;
    int deg = 0, lrank = 0;
    if (i < N) {
        int o = offs[i] + sb[i >> 10];
        offs[i] = o;
        cursor[i] = o;
        int c = cnt[i];
        deg = c < DBINS ? c : DBINS - 1;
        lrank = atomicAdd(&lcnt[deg], 1);          // local rank within block
    }
    __syncthreads();
    if (tid < DBINS) {
        int n = lcnt[tid];
        lbase[tid] = (n > 0) ? (dbs[tid] + atomicAdd(bincur + tid, n)) : 0;
    }
    __syncthreads();
    if (i < N) order[lbase[deg] + lrank] = i;
}

// ---------------- K2: CSR slot-fill: packed tail|rel<<20 per slot ----------------
__global__ __launch_bounds__(256) void k_csr(
    const int* __restrict__ heads, const int* __restrict__ rels,
    const int* __restrict__ tails, int* __restrict__ cursor,
    int* __restrict__ trp, int E)
{
    int e = blockIdx.x * 256 + threadIdx.x;
    if (e >= E) return;
    int pos = atomicAdd(cursor + heads[e], 1);
    trp[pos] = tails[e] | (rels[e] << 20);
}

// ---------------- K3: fused score + online-softmax aggregate ----------------
// 16 lanes per head; DESCENDING degree order (LPT). Gate via exp factorization:
// exp2(C*(h+r)) = ehr[i] * relE[r][i] -- ehr computed once per head (8 trans),
// relE is a 32 KB L2-resident table. Per element: 1 mul + 1 add + 1 rcp + 2 fma
// (was +1 exp +1 add). Structure/prefetch identical to the verified r8 body.
__global__ __launch_bounds__(256) void k_fused(
    const short* __restrict__ entb, const float* __restrict__ relE,
    const int* __restrict__ offs, const int* __restrict__ cnt,
    const int* __restrict__ trp, const int* __restrict__ order,
    short* __restrict__ accb, float* __restrict__ mh, float* __restrict__ lh,
    float* __restrict__ blockmax, int N)
{
    const int tid = threadIdx.x;
    const int lane = tid & 15;
    int head0 = blockIdx.x * 16 + (tid >> 4);
    int head  = (head0 < N) ? order[(N - 1) - head0] : N;   // reverse = descending degree
    float mt = -INFINITY;              // true max (for global M)
    if (head < N) {
        int start = offs[head];
        int c     = cnt[head];
        short8 hh = *((const short8*)(entb + (size_t)head * EMBED) + lane);
        float ehr[8];
        #pragma unroll
        for (int i = 0; i < 8; ++i) ehr[i] = ex2(TWO_LOG2E * b2f(hh[i]));
        float m = -INFINITY;           // deferred reference point
        float l = 0.f;
        float acc[8] = {0,0,0,0,0,0,0,0};
        for (int base = 0; base < c; base += 16) {
            int rem = c - base;
            int mm  = rem < 16 ? rem : 16;
            int trv = 0;
            if (lane < mm) trv = trp[start + base + lane];
            int p0 = __shfl(trv, 0, 16);
            short8 vtc = *((const short8*)(entb + (size_t)(p0 & TMASK) * EMBED) + lane);
            const float4* ep0 = (const float4*)(relE + (size_t)(p0 >> 20) * EMBED) + lane * 2;
            float4 erc0 = ep0[0], erc1 = ep0[1];
            for (int j = 0; j < mm; ++j) {
                int jn = (j + 1 < mm) ? j + 1 : j;       // clamp: last iter reloads (cache-hot)
                int pn = __shfl(trv, jn, 16);
                short8 vtn = *((const short8*)(entb + (size_t)(pn & TMASK) * EMBED) + lane);
                const float4* epn = (const float4*)(relE + (size_t)(pn >> 20) * EMBED) + lane * 2;
                float4 ern0 = epn[0], ern1 = epn[1];
                float er[8] = {erc0.x, erc0.y, erc0.z, erc0.w,
                               erc1.x, erc1.y, erc1.z, erc1.w};
                float s = 0.f;
                float vtf[8];
                #pragma unroll
                for (int i = 0; i < 8; ++i) {
                    vtf[i] = b2f(vtc[i]);
                    float e = ehr[i] * er[i];                       // exp2(C*(h+r))
                    float cc = __builtin_amdgcn_rcpf(1.0f + e);
                    s = fmaf(vtf[i], 1.0f - 2.0f * cc, s);          // t * tanh(h+r)
                }
                s = dpp_sum16(s);
                mt = fmaxf(mt, s);
                float dlt = s - m;                 // first edge: +inf
                if (dlt > DEFER_THR) {             // rare after j=0 (j=0 synchronized)
                    float alpha = __expf(-dlt);    // exp(m - s); -inf -> 0
                    l *= alpha;
                    #pragma unroll
                    for (int q = 0; q < 8; ++q) acc[q] *= alpha;
                    m = s;
                    dlt = 0.f;
                }
                float p = __expf(dlt);             // p <= e^32: fp32-safe
                l += p;
                #pragma unroll
                for (int q = 0; q < 8; ++q)
                    acc[q] = fmaf(p, vtf[q], acc[q]);
                vtc = vtn;
                erc0 = ern0;
                erc1 = ern1;
            }
        }
        short8 o;
        #pragma unroll
        for (int q = 0; q < 8; ++q) o[q] = (short)f2b(acc[q]);
        *((short8*)(accb + (size_t)head * EMBED) + lane) = o;
        if (lane == 0) { mh[head] = m; lh[head] = l; }
    }
    // block max: wave shfl_xor reduce + 4-slot LDS + one barrier
    __shared__ float wmax[4];
    float wm = mt;
    #pragma unroll
    for (int off = 1; off < 64; off <<= 1) wm = fmaxf(wm, __shfl_xor(wm, off, 64));
    if ((tid & 63) == 0) wmax[tid >> 6] = wm;
    __syncthreads();
    if (tid == 0)
        blockmax[blockIdx.x] = fmaxf(fmaxf(wmax[0], wmax[1]), fmaxf(wmax[2], wmax[3]));
}

// ---------------- K4: maxred (folded) + normalize + x = ent + agg + bf16 MFMA GEMM ----------------
// Each block reduces blockmax[] (25 KB, L2-broadcast-hot; no atomics/fences)
// to get M, then computes invs and the MFMA GEMM with register-built
// A-fragments (no xs LDS round-trip).
__global__ __launch_bounds__(256) void k_gemm_f(
    const short* __restrict__ entb, const short* __restrict__ accb,
    const float* __restrict__ mh, const float* __restrict__ lh,
    const float* __restrict__ blockmax, int nbm, const short* __restrict__ wb,
    float* __restrict__ out, int N)
{
    __shared__ short ws[128 * LDSPAD];
    __shared__ float invs[128];
    __shared__ float wmax[4];
    const int tid = threadIdx.x;
    const int n0  = blockIdx.x * 128;

    // M = max(blockmax[0..nbm)) -- per-block reduce, no atomics
    float m2 = -INFINITY;
    for (int i = tid; i < nbm; i += 256) m2 = fmaxf(m2, blockmax[i]);
    #pragma unroll
    for (int off = 1; off < 64; off <<= 1) m2 = fmaxf(m2, __shfl_xor(m2, off, 64));
    if ((tid & 63) == 0) wmax[tid >> 6] = m2;
    __syncthreads();
    const float M = fmaxf(fmaxf(wmax[0], wmax[1]), fmaxf(wmax[2], wmax[3]));

    if (tid < 128) {
        int g = n0 + tid;
        invs[tid] = (g < N) ? 1.0f / (lh[g] + 1e-10f * __expf(M - mh[g])) : 0.f;  // inf -> 0
    }
    // stage W (pre-cast bf16): 2048 short8 chunks, 8 per thread
    #pragma unroll
    for (int it = 0; it < 8; ++it) {
        int ch = it * 256 + tid;
        int row = ch >> 4, col8 = ch & 15;
        *(short8*)(ws + row * LDSPAD + col8 * 8) = ((const short8*)wb)[ch];
    }
    __syncthreads();

    const int wv   = tid >> 6;
    const int lane = tid & 63;
    const int n16  = lane & 15;
    const int quad = lane >> 4;

    const int lr0 = wv * 32 + n16;        // local row of a0
    const int lr1 = lr0 + 16;             // local row of a1
    const int g0  = n0 + lr0;
    const int g1  = n0 + lr1;

    floatx4 acc[2][8];
    #pragma unroll
    for (int rt = 0; rt < 2; ++rt)
        #pragma unroll
        for (int jt = 0; jt < 8; ++jt)
            acc[rt][jt] = (floatx4){0.f, 0.f, 0.f, 0.f};

    const float inv0 = invs[lr0];
    const float inv1 = invs[lr1];

    #pragma unroll
    for (int kc = 0; kc < 4; ++kc) {
        int koff = kc * 32 + quad * 8;
        short8 a0 = {0,0,0,0,0,0,0,0};
        short8 a1 = {0,0,0,0,0,0,0,0};
        if (g0 < N) {
            short8 e8 = *(const short8*)(entb + (size_t)g0 * EMBED + koff);
            short8 a8 = *(const short8*)(accb + (size_t)g0 * EMBED + koff);
            #pragma unroll
            for (int q = 0; q < 8; ++q)
                a0[q] = (short)f2b(b2f(e8[q]) + b2f(a8[q]) * inv0);
        }
        if (g1 < N) {
            short8 e8 = *(const short8*)(entb + (size_t)g1 * EMBED + koff);
            short8 a8 = *(const short8*)(accb + (size_t)g1 * EMBED + koff);
            #pragma unroll
            for (int q = 0; q < 8; ++q)
                a1[q] = (short)f2b(b2f(e8[q]) + b2f(a8[q]) * inv1);
        }
        #pragma unroll
        for (int jt = 0; jt < 8; ++jt) {
            short8 b = *(const short8*)(ws + (jt * 16 + n16) * LDSPAD + koff);
            acc[0][jt] = __builtin_amdgcn_mfma_f32_16x16x32_bf16(a0, b, acc[0][jt], 0, 0, 0);
            acc[1][jt] = __builtin_amdgcn_mfma_f32_16x16x32_bf16(a1, b, acc[1][jt], 0, 0, 0);
        }
    }

    #pragma unroll
    for (int rt = 0; rt < 2; ++rt) {
        int rowbase = n0 + wv * 32 + rt * 16 + quad * 4;
        #pragma unroll
        for (int r = 0; r < 4; ++r) {
            int grow = rowbase + r;
            if (grow < N) {
                float* o = out + (size_t)grow * EMBED + n16;
                #pragma unroll
                for (int jt = 0; jt < 8; ++jt) {
                    float v = acc[rt][jt][r];
                    o[jt * 16] = (v > 0.f) ? v : 0.2f * v;
                }
            }
        }
    }
}

extern "C" void kernel_launch(void* const* d_in, const int* in_sizes, int n_in,
                              void* d_out, int out_size, void* d_ws, size_t ws_size,
                              hipStream_t stream)
{
    const float* ent   = (const float*)d_in[0];   // entity_emb  [N,128] fp32
    const float* rel   = (const float*)d_in[1];   // rel_embed   [R,128] fp32
    const float* W     = (const float*)d_in[2];   // W           [128,128] fp32
    const int*   heads = (const int*)d_in[3];
    const int*   rels  = (const int*)d_in[4];
    const int*   tails = (const int*)d_in[5];
    const int E = in_sizes[3];
    const int N = in_sizes[0] / EMBED;
    const int R = in_sizes[1] / EMBED;
    float* out = (float*)d_out;

    // ws layout:
    // accb[N*128]s | mh[N]f | lh[N]f | trp[E]i | cnt[N]i | bincur[64]i | offs[N]i |
    // cursor[N]i | blockmax[BMAX]f | bsum[1024]i | ghist[64]i | order[N]i |
    // wb[16384]s | relE[R*128]f | entb[N*128]s
    short* accb     = (short*)d_ws;
    float* mh       = (float*)(accb + (size_t)N * EMBED);
    float* lh       = mh + N;
    int*   trp      = (int*)(lh + N);
    int*   cnt      = trp + E;
    int*   bincur   = cnt + N;                      // zeroed together with cnt
    int*   offs     = bincur + DBINS;
    int*   cursor   = offs + N;
    float* blockmax = (float*)(cursor + N);
    int*   bsum     = (int*)(blockmax + BMAX);
    int*   ghist    = bsum + 1024;
    int*   order    = ghist + DBINS;
    short* wb       = (short*)(order + N);          // 128*128 bf16 = 32 KB
    float* relE     = (float*)(wb + 16384);         // R*128 f32 = 32 KB (R=64)
    short* entb     = (short*)(relE + (size_t)R * EMBED);

    const int nb  = (N + 1023) >> 10;       // scan blocks (<= 256 assumed: N <= 262144)
    const int ngh = (N + 15) / 16;          // per-head group blocks

    hipMemsetAsync(cnt, 0, (size_t)(N + DBINS) * sizeof(int), stream);

    int ngE = N * EMBED / 8, ngW = EMBED * EMBED / 8, ngX = R * EMBED / 8;
    k_cast_hist<<<2048, 256, 0, stream>>>(ent, rel, W, entb, wb, relE, heads, cnt, ghist, ngE, ngW, ngX, E);
    k_scan1<<<nb, 1024, 0, stream>>>(cnt, offs, bsum, ghist, N);
    k_scan23<<<(N + 255) / 256, 256, 0, stream>>>(offs, bsum, cursor, cnt, ghist, bincur, order, N, nb);
    k_csr<<<(E + 255) / 256, 256, 0, stream>>>(heads, rels, tails, cursor, trp, E);
    k_fused<<<ngh, 256, 0, stream>>>(entb, relE, offs, cnt, trp, order, accb, mh, lh, blockmax, N);
    k_gemm_f<<<(N + 127) / 128, 256, 0, stream>>>(entb, accb, mh, lh, blockmax, ngh, wb, out, N);
}

// Round 13
// 227.551 us; speedup vs baseline: 2.0335x; 1.0260x over previous
//
#include <hip/hip_runtime.h>
#include <math.h>

#define EMBED 128
#define BMAX 8192    // blockmax array (fused grid = ceil(N/16) = 6250 <= BMAX)
#define LDSPAD 136   // 128 + 8 bf16 pad -> 272 B row stride
#define DBINS 64     // degree bins for counting sort (deg clamped to 63)

#define TWO_LOG2E 2.8853900817779268f
#define DEFER_THR 32.0f

// (tail, rel) packed: tail in bits [0,20), rel in bits [20,32). Requires
// N < 2^20 (here N=100000) and R < 2^12 (here 64).
#define TMASK 0xFFFFF

typedef __attribute__((ext_vector_type(8))) short short8;
typedef __attribute__((ext_vector_type(4))) float floatx4;

__device__ __forceinline__ float ex2(float x) { return __builtin_amdgcn_exp2f(x); }

__device__ __forceinline__ unsigned short f2b(float f) {   // fp32 -> bf16 RNE
    union { float f; unsigned int u; } v; v.f = f;
    unsigned int r = v.u + 0x7FFFu + ((v.u >> 16) & 1u);
    return (unsigned short)(r >> 16);
}

__device__ __forceinline__ float b2f(short u) {
    union { float f; unsigned int i; } v;
    v.i = ((unsigned int)(unsigned short)u) << 16;
    return v.f;
}

// sum over the 16-lane DPP row via sum-of-rotations (exact allreduce)
template <int CTRL>
__device__ __forceinline__ float dpp_add_f(float x) {
    int y = __builtin_amdgcn_update_dpp(0, __float_as_int(x), CTRL, 0xF, 0xF, false);
    return x + __int_as_float(y);
}
__device__ __forceinline__ float dpp_sum16(float s) {
    s = dpp_add_f<0x121>(s);   // row_ror:1
    s = dpp_add_f<0x122>(s);   // row_ror:2
    s = dpp_add_f<0x124>(s);   // row_ror:4
    s = dpp_add_f<0x128>(s);   // row_ror:8
    return s;
}

__device__ __forceinline__ short8 cvt8(float4 a, float4 b) {
    short8 o;
    o[0] = (short)f2b(a.x); o[1] = (short)f2b(a.y); o[2] = (short)f2b(a.z); o[3] = (short)f2b(a.w);
    o[4] = (short)f2b(b.x); o[5] = (short)f2b(b.y); o[6] = (short)f2b(b.z); o[7] = (short)f2b(b.w);
    return o;
}

// ---------------- K0: cast ent/W to bf16, build relE = exp2(C*rel) f32 table,
//                     head histogram (+ zero ghist) ----------------
// Hot loop is branch-free pure-ent cast, 2-way unrolled (4 dwordx4 in flight
// per thread) -- the r11 version was latency-bound at VALUBusy 3.9%.
// W + relE (3072 chunks) handled by a one-shot prologue on low global ids.
__global__ __launch_bounds__(256) void k_cast_hist(
    const float* __restrict__ ent, const float* __restrict__ rel, const float* __restrict__ W,
    short* __restrict__ entb, short* __restrict__ wb, float* __restrict__ relE,
    const int* __restrict__ heads, int* __restrict__ cnt, int* __restrict__ ghist,
    int ngE, int ngW, int ngX, int E)
{
    const int tid = threadIdx.x;
    const int gid = blockIdx.x * 256 + tid;
    const int stride = gridDim.x * 256;
    if (blockIdx.x == 0 && tid < DBINS) ghist[tid] = 0;  // no reader until k_scan1

    // prologue: W -> wb (bf16), rel -> relE (exp2 table). one chunk per low gid.
    if (gid < ngW + ngX) {
        if (gid < ngW) {
            const float4* src = (const float4*)W + (size_t)gid * 2;
            *(short8*)(wb + (size_t)gid * 8) = cvt8(src[0], src[1]);
        } else {
            int g2 = gid - ngW;
            const float4* src = (const float4*)rel + (size_t)g2 * 2;
            float4 a = src[0], b = src[1];
            float4 ea, eb;
            ea.x = ex2(TWO_LOG2E * a.x); ea.y = ex2(TWO_LOG2E * a.y);
            ea.z = ex2(TWO_LOG2E * a.z); ea.w = ex2(TWO_LOG2E * a.w);
            eb.x = ex2(TWO_LOG2E * b.x); eb.y = ex2(TWO_LOG2E * b.y);
            eb.z = ex2(TWO_LOG2E * b.z); eb.w = ex2(TWO_LOG2E * b.w);
            float4* dst = (float4*)(relE + (size_t)g2 * 8);
            dst[0] = ea; dst[1] = eb;
        }
    }

    // hot loop: ent cast, branch-free, 2 chunks per iteration
    for (int g = gid; g < ngE; g += 2 * stride) {
        const float4* s0 = (const float4*)ent + (size_t)g * 2;
        float4 a0 = s0[0], b0 = s0[1];
        int g1 = g + stride;
        bool has1 = g1 < ngE;
        float4 a1 = {0,0,0,0}, b1 = {0,0,0,0};
        if (has1) {
            const float4* s1 = (const float4*)ent + (size_t)g1 * 2;
            a1 = s1[0]; b1 = s1[1];
        }
        *(short8*)(entb + (size_t)g * 8) = cvt8(a0, b0);
        if (has1)
            *(short8*)(entb + (size_t)g1 * 8) = cvt8(a1, b1);
    }

    for (int e = gid; e < E; e += stride)
        atomicAdd(cnt + heads[e], 1);
}

// ---------------- K1a: block scan of cnt + degree histogram ----------------
__global__ __launch_bounds__(1024) void k_scan1(
    const int* __restrict__ cnt, int* __restrict__ offs,
    int* __restrict__ bsum, int* __restrict__ ghist, int N)
{
    __shared__ int wsum[16];
    __shared__ int dh[DBINS];
    const int tid = threadIdx.x;
    if (tid < DBINS) dh[tid] = 0;
    int i = blockIdx.x * 1024 + tid;
    int v = (i < N) ? cnt[i] : 0;
    __syncthreads();
    if (i < N) atomicAdd(&dh[v < DBINS ? v : DBINS - 1], 1);
    int x = v;
    #pragma unroll
    for (int d = 1; d < 64; d <<= 1) {
        int y = __shfl_up(x, d, 64);
        if ((tid & 63) >= d) x += y;
    }
    if ((tid & 63) == 63) wsum[tid >> 6] = x;
    __syncthreads();
    if (tid < 16) {
        int w = wsum[tid];
        #pragma unroll
        for (int d = 1; d < 16; d <<= 1) {
            int y = __shfl_up(w, d, 16);
            if (tid >= d) w += y;
        }
        wsum[tid] = w;
    }
    __syncthreads();
    int add = (tid >= 64) ? wsum[(tid >> 6) - 1] : 0;
    int incl = x + add;
    if (i < N) offs[i] = incl - v;
    if (tid == 1023) bsum[blockIdx.x] = incl;
    if (tid < DBINS && dh[tid] > 0) atomicAdd(ghist + tid, dh[tid]);
}

// ---------------- K1b: finalize offs/cursor + counting-sort scatter (scan2 folded in) ----------------
__global__ __launch_bounds__(256) void k_scan23(
    int* __restrict__ offs, const int* __restrict__ bsum,
    int* __restrict__ cursor, const int* __restrict__ cnt,
    const int* __restrict__ ghist, int* __restrict__ bincur,
    int* __restrict__ order, int N, int nb)
{
    __shared__ int sb[256];      // exclusive-scanned bsum
    __shared__ int ws4[4];
    __shared__ int dbs[DBINS];   // exclusive-scanned ghist
    __shared__ int lcnt[DBINS];
    __shared__ int lbase[DBINS];
    const int tid = threadIdx.x;

    int v = (tid < nb) ? bsum[tid] : 0;
    int x = v;
    #pragma unroll
    for (int d = 1; d < 64; d <<= 1) {
        int y = __shfl_up(x, d, 64);
        if ((tid & 63) >= d) x += y;
    }
    if ((tid & 63) == 63) ws4[tid >> 6] = x;
    __syncthreads();
    if (tid < 4) {
        int w = ws4[tid];
        #pragma unroll
        for (int d = 1; d < 4; d <<= 1) {
            int y = __shfl_up(w, d, 4);
            if (tid >= d) w += y;
        }
        ws4[tid] = w;
    }
    __syncthreads();
    int add = (tid >= 64) ? ws4[(tid >> 6) - 1] : 0;
    sb[tid] = x + add - v;            // exclusive prefix of bsum

    if (tid < 64) {                   // ghist exclusive scan (one wave)
        int g = ghist[tid];
        int s = g;
        #pragma unroll
        for (int d = 1; d < 64; d <<= 1) {
            int y = __shfl_up(s, d, 64);
            if (tid >= d) s += y;
        }
        dbs[tid] = s - g;
    }
    if (tid < DBINS) lcnt[tid] = 0;
    __syncthreads();

    int i = blockIdx.x * 256 + tid;
    int deg = 0, lrank = 0;
    if (i < N) {
        int o = offs[i] + sb[i >> 10];
        offs[i] = o;
        cursor[i] = o;
        int c = cnt[i];
        deg = c < DBINS ? c : DBINS - 1;
        lrank = atomicAdd(&lcnt[deg], 1);          // local rank within block
    }
    __syncthreads();
    if (tid < DBINS) {
        int n = lcnt[tid];
        lbase[tid] = (n > 0) ? (dbs[tid] + atomicAdd(bincur + tid, n)) : 0;
    }
    __syncthreads();
    if (i < N) order[lbase[deg] + lrank] = i;
}

// ---------------- K2: CSR slot-fill: packed tail|rel<<20 per slot ----------------
__global__ __launch_bounds__(256) void k_csr(
    const int* __restrict__ heads, const int* __restrict__ rels,
    const int* __restrict__ tails, int* __restrict__ cursor,
    int* __restrict__ trp, int E)
{
    int e = blockIdx.x * 256 + threadIdx.x;
    if (e >= E) return;
    int pos = atomicAdd(cursor + heads[e], 1);
    trp[pos] = tails[e] | (rels[e] << 20);
}

// ---------------- K3: fused score + online-softmax aggregate ----------------
// 16 lanes per head; DESCENDING degree order (LPT). Gate via exp factorization:
// exp2(C*(h+r)) = ehr[i] * relE[r][i]. Byte-identical to the verified r11 body.
__global__ __launch_bounds__(256) void k_fused(
    const short* __restrict__ entb, const float* __restrict__ relE,
    const int* __restrict__ offs, const int* __restrict__ cnt,
    const int* __restrict__ trp, const int* __restrict__ order,
    short* __restrict__ accb, float* __restrict__ mh, float* __restrict__ lh,
    float* __restrict__ blockmax, int N)
{
    const int tid = threadIdx.x;
    const int lane = tid & 15;
    int head0 = blockIdx.x * 16 + (tid >> 4);
    int head  = (head0 < N) ? order[(N - 1) - head0] : N;   // reverse = descending degree
    float mt = -INFINITY;              // true max (for global M)
    if (head < N) {
        int start = offs[head];
        int c     = cnt[head];
        short8 hh = *((const short8*)(entb + (size_t)head * EMBED) + lane);
        float ehr[8];
        #pragma unroll
        for (int i = 0; i < 8; ++i) ehr[i] = ex2(TWO_LOG2E * b2f(hh[i]));
        float m = -INFINITY;           // deferred reference point
        float l = 0.f;
        float acc[8] = {0,0,0,0,0,0,0,0};
        for (int base = 0; base < c; base += 16) {
            int rem = c - base;
            int mm  = rem < 16 ? rem : 16;
            int trv = 0;
            if (lane < mm) trv = trp[start + base + lane];
            int p0 = __shfl(trv, 0, 16);
            short8 vtc = *((const short8*)(entb + (size_t)(p0 & TMASK) * EMBED) + lane);
            const float4* ep0 = (const float4*)(relE + (size_t)(p0 >> 20) * EMBED) + lane * 2;
            float4 erc0 = ep0[0], erc1 = ep0[1];
            for (int j = 0; j < mm; ++j) {
                int jn = (j + 1 < mm) ? j + 1 : j;       // clamp: last iter reloads (cache-hot)
                int pn = __shfl(trv, jn, 16);
                short8 vtn = *((const short8*)(entb + (size_t)(pn & TMASK) * EMBED) + lane);
                const float4* epn = (const float4*)(relE + (size_t)(pn >> 20) * EMBED) + lane * 2;
                float4 ern0 = epn[0], ern1 = epn[1];
                float er[8] = {erc0.x, erc0.y, erc0.z, erc0.w,
                               erc1.x, erc1.y, erc1.z, erc1.w};
                float s = 0.f;
                float vtf[8];
                #pragma unroll
                for (int i = 0; i < 8; ++i) {
                    vtf[i] = b2f(vtc[i]);
                    float e = ehr[i] * er[i];                       // exp2(C*(h+r))
                    float cc = __builtin_amdgcn_rcpf(1.0f + e);
                    s = fmaf(vtf[i], 1.0f - 2.0f * cc, s);          // t * tanh(h+r)
                }
                s = dpp_sum16(s);
                mt = fmaxf(mt, s);
                float dlt = s - m;                 // first edge: +inf
                if (dlt > DEFER_THR) {             // rare after j=0 (j=0 synchronized)
                    float alpha = __expf(-dlt);    // exp(m - s); -inf -> 0
                    l *= alpha;
                    #pragma unroll
                    for (int q = 0; q < 8; ++q) acc[q] *= alpha;
                    m = s;
                    dlt = 0.f;
                }
                float p = __expf(dlt);             // p <= e^32: fp32-safe
                l += p;
                #pragma unroll
                for (int q = 0; q < 8; ++q)
                    acc[q] = fmaf(p, vtf[q], acc[q]);
                vtc = vtn;
                erc0 = ern0;
                erc1 = ern1;
            }
        }
        short8 o;
        #pragma unroll
        for (int q = 0; q < 8; ++q) o[q] = (short)f2b(acc[q]);
        *((short8*)(accb + (size_t)head * EMBED) + lane) = o;
        if (lane == 0) { mh[head] = m; lh[head] = l; }
    }
    // block max: wave shfl_xor reduce + 4-slot LDS + one barrier
    __shared__ float wmax[4];
    float wm = mt;
    #pragma unroll
    for (int off = 1; off < 64; off <<= 1) wm = fmaxf(wm, __shfl_xor(wm, off, 64));
    if ((tid & 63) == 0) wmax[tid >> 6] = wm;
    __syncthreads();
    if (tid == 0)
        blockmax[blockIdx.x] = fmaxf(fmaxf(wmax[0], wmax[1]), fmaxf(wmax[2], wmax[3]));
}

// ---------------- K4: maxred (folded) + normalize + x = ent + agg + bf16 MFMA GEMM ----------------
// 256 rows per block, processed as two 128-row tiles: W stage + blockmax
// reduce amortized over 2x the rows (halves W traffic + block count).
// A-fragments built in registers; acc reused across tiles (VGPR unchanged).
// NOTE: the per-half early-exit is BLOCK-UNIFORM (n0 depends only on
// blockIdx/half), so the barriers inside the loop are safe.
__global__ __launch_bounds__(256) void k_gemm_f(
    const short* __restrict__ entb, const short* __restrict__ accb,
    const float* __restrict__ mh, const float* __restrict__ lh,
    const float* __restrict__ blockmax, int nbm, const short* __restrict__ wb,
    float* __restrict__ out, int N)
{
    __shared__ short ws[128 * LDSPAD];
    __shared__ float invs[128];
    __shared__ float wmax[4];
    const int tid = threadIdx.x;

    // M = max(blockmax[0..nbm)) -- per-block reduce, no atomics
    float m2 = -INFINITY;
    for (int i = tid; i < nbm; i += 256) m2 = fmaxf(m2, blockmax[i]);
    #pragma unroll
    for (int off = 1; off < 64; off <<= 1) m2 = fmaxf(m2, __shfl_xor(m2, off, 64));
    if ((tid & 63) == 0) wmax[tid >> 6] = m2;
    __syncthreads();
    const float M = fmaxf(fmaxf(wmax[0], wmax[1]), fmaxf(wmax[2], wmax[3]));

    // stage W (pre-cast bf16): 2048 short8 chunks, 8 per thread -- once per block
    #pragma unroll
    for (int it = 0; it < 8; ++it) {
        int ch = it * 256 + tid;
        int row = ch >> 4, col8 = ch & 15;
        *(short8*)(ws + row * LDSPAD + col8 * 8) = ((const short8*)wb)[ch];
    }

    const int wv   = tid >> 6;
    const int lane = tid & 63;
    const int n16  = lane & 15;
    const int quad = lane >> 4;

    #pragma unroll
    for (int half = 0; half < 2; ++half) {
        const int n0 = blockIdx.x * 256 + half * 128;   // block-uniform
        if (n0 >= N) break;
        __syncthreads();           // ws ready (half 0) / prior invs readers done (half 1)
        if (tid < 128) {
            int g = n0 + tid;
            invs[tid] = (g < N) ? 1.0f / (lh[g] + 1e-10f * __expf(M - mh[g])) : 0.f;  // inf -> 0
        }
        __syncthreads();

        const int lr0 = wv * 32 + n16;        // local row of a0
        const int lr1 = lr0 + 16;             // local row of a1
        const int g0  = n0 + lr0;
        const int g1  = n0 + lr1;

        floatx4 acc[2][8];
        #pragma unroll
        for (int rt = 0; rt < 2; ++rt)
            #pragma unroll
            for (int jt = 0; jt < 8; ++jt)
                acc[rt][jt] = (floatx4){0.f, 0.f, 0.f, 0.f};

        const float inv0 = invs[lr0];
        const float inv1 = invs[lr1];

        #pragma unroll
        for (int kc = 0; kc < 4; ++kc) {
            int koff = kc * 32 + quad * 8;
            short8 a0 = {0,0,0,0,0,0,0,0};
            short8 a1 = {0,0,0,0,0,0,0,0};
            if (g0 < N) {
                short8 e8 = *(const short8*)(entb + (size_t)g0 * EMBED + koff);
                short8 a8 = *(const short8*)(accb + (size_t)g0 * EMBED + koff);
                #pragma unroll
                for (int q = 0; q < 8; ++q)
                    a0[q] = (short)f2b(b2f(e8[q]) + b2f(a8[q]) * inv0);
            }
            if (g1 < N) {
                short8 e8 = *(const short8*)(entb + (size_t)g1 * EMBED + koff);
                short8 a8 = *(const short8*)(accb + (size_t)g1 * EMBED + koff);
                #pragma unroll
                for (int q = 0; q < 8; ++q)
                    a1[q] = (short)f2b(b2f(e8[q]) + b2f(a8[q]) * inv1);
            }
            #pragma unroll
            for (int jt = 0; jt < 8; ++jt) {
                short8 b = *(const short8*)(ws + (jt * 16 + n16) * LDSPAD + koff);
                acc[0][jt] = __builtin_amdgcn_mfma_f32_16x16x32_bf16(a0, b, acc[0][jt], 0, 0, 0);
                acc[1][jt] = __builtin_amdgcn_mfma_f32_16x16x32_bf16(a1, b, acc[1][jt], 0, 0, 0);
            }
        }

        #pragma unroll
        for (int rt = 0; rt < 2; ++rt) {
            int rowbase = n0 + wv * 32 + rt * 16 + quad * 4;
            #pragma unroll
            for (int r = 0; r < 4; ++r) {
                int grow = rowbase + r;
                if (grow < N) {
                    float* o = out + (size_t)grow * EMBED + n16;
                    #pragma unroll
                    for (int jt = 0; jt < 8; ++jt) {
                        float v = acc[rt][jt][r];
                        o[jt * 16] = (v > 0.f) ? v : 0.2f * v;
                    }
                }
            }
        }
    }
}

extern "C" void kernel_launch(void* const* d_in, const int* in_sizes, int n_in,
                              void* d_out, int out_size, void* d_ws, size_t ws_size,
                              hipStream_t stream)
{
    const float* ent   = (const float*)d_in[0];   // entity_emb  [N,128] fp32
    const float* rel   = (const float*)d_in[1];   // rel_embed   [R,128] fp32
    const float* W     = (const float*)d_in[2];   // W           [128,128] fp32
    const int*   heads = (const int*)d_in[3];
    const int*   rels  = (const int*)d_in[4];
    const int*   tails = (const int*)d_in[5];
    const int E = in_sizes[3];
    const int N = in_sizes[0] / EMBED;
    const int R = in_sizes[1] / EMBED;
    float* out = (float*)d_out;

    // ws layout:
    // accb[N*128]s | mh[N]f | lh[N]f | trp[E]i | cnt[N]i | bincur[64]i | offs[N]i |
    // cursor[N]i | blockmax[BMAX]f | bsum[1024]i | ghist[64]i | order[N]i |
    // wb[16384]s | relE[R*128]f | entb[N*128]s
    short* accb     = (short*)d_ws;
    float* mh       = (float*)(accb + (size_t)N * EMBED);
    float* lh       = mh + N;
    int*   trp      = (int*)(lh + N);
    int*   cnt      = trp + E;
    int*   bincur   = cnt + N;                      // zeroed together with cnt
    int*   offs     = bincur + DBINS;
    int*   cursor   = offs + N;
    float* blockmax = (float*)(cursor + N);
    int*   bsum     = (int*)(blockmax + BMAX);
    int*   ghist    = bsum + 1024;
    int*   order    = ghist + DBINS;
    short* wb       = (short*)(order + N);          // 128*128 bf16 = 32 KB
    float* relE     = (float*)(wb + 16384);         // R*128 f32 = 32 KB (R=64)
    short* entb     = (short*)(relE + (size_t)R * EMBED);

    const int nb  = (N + 1023) >> 10;       // scan blocks (<= 256 assumed: N <= 262144)
    const int ngh = (N + 15) / 16;          // per-head group blocks

    hipMemsetAsync(cnt, 0, (size_t)(N + DBINS) * sizeof(int), stream);

    int ngE = N * EMBED / 8, ngW = EMBED * EMBED / 8, ngX = R * EMBED / 8;
    k_cast_hist<<<2048, 256, 0, stream>>>(ent, rel, W, entb, wb, relE, heads, cnt, ghist, ngE, ngW, ngX, E);
    k_scan1<<<nb, 1024, 0, stream>>>(cnt, offs, bsum, ghist, N);
    k_scan23<<<(N + 255) / 256, 256, 0, stream>>>(offs, bsum, cursor, cnt, ghist, bincur, order, N, nb);
    k_csr<<<(E + 255) / 256, 256, 0, stream>>>(heads, rels, tails, cursor, trp, E);
    k_fused<<<ngh, 256, 0, stream>>>(entb, relE, offs, cnt, trp, order, accb, mh, lh, blockmax, N);
    k_gemm_f<<<(N + 255) / 256, 256, 0, stream>>>(entb, accb, mh, lh, blockmax, ngh, wb, out, N);
}